// Round 7
// baseline (208.094 us; speedup 1.0000x reference)
//
#include <hip/hip_runtime.h>

// RecurrentDecoder: B=8192, T=100, I=30, H=100.
// Occupancy-focused rebuild: B-tile=16, 512 blocks x 512 threads, each wave
// owns ONE 16-unit tile x 4 gates (wfrag 64 regs). Target <=128 regs/lane ->
// 2 blocks/CU -> 4 waves/SIMD. Bias folded into constant h-channel 100 (=1.0).
// No VMEM in the step loop (LDS outb, epilogue write). One barrier per step.

#define LOG2E 1.44269504088896340736f

typedef _Float16 f16x8 __attribute__((ext_vector_type(8)));
typedef _Float16 f16x2v __attribute__((ext_vector_type(2)));
typedef float    f32x4 __attribute__((ext_vector_type(4)));

__device__ __forceinline__ float rcp_(float x) { return __builtin_amdgcn_rcpf(x); }
__device__ __forceinline__ float exp2_(float x) { return __builtin_amdgcn_exp2f(x); }

__device__ __forceinline__ unsigned pk_f16(float a, float b) {
    return __builtin_bit_cast(unsigned, __builtin_amdgcn_cvt_pkrtz(a, b));
}

template<int CTRL>
__device__ __forceinline__ float dpp_add(float x) {
    float t = __int_as_float(__builtin_amdgcn_update_dpp(
        0, __float_as_int(x), CTRL, 0xF, 0xF, true));
    return x + t;
}

#define KS 136   // f16 k-stride (272 B, 16B-aligned; proven in R6)

__global__ __launch_bounds__(512, 4) void lstm_kernel(
    const float* __restrict__ x, const float* __restrict__ Wih,
    const float* __restrict__ Whh, const float* __restrict__ bih,
    const float* __restrict__ bhh, const float* __restrict__ Wd,
    const float* __restrict__ bd, float* __restrict__ out)
{
    __shared__ __align__(16) _Float16 Wstg[128 * KS];     // 34816 B (per-gate chunk)
    __shared__ __align__(16) _Float16 hlds[2][16 * KS];   //  8704 B (dbuf)
    __shared__ float part[2][16][8];                      //  1024 B
    __shared__ float outb[16 * 100];                      //  6400 B
    // total ~51 KB -> 2 blocks/CU (LDS-wise)

    const int tid = threadIdx.x;
    const int w   = tid >> 6;      // wave 0..7 = unit-tile
    const int l   = tid & 63;
    const int g   = l >> 4;        // 0..3 -> rows 4g..4g+3
    const int c   = l & 15;        // unit within tile
    const int u   = w * 16 + c;    // this lane's unit (0..127; >=100 pad)
    const int b0  = blockIdx.x * 16;

    // ---- zero staging + h buffers (covers all padding) ----
    for (int i = tid; i < 128 * KS / 2; i += 512) ((unsigned*)Wstg)[i] = 0u;
    for (int i = tid; i < 2 * 16 * KS / 2; i += 512) ((unsigned*)&hlds[0][0])[i] = 0u;
    __syncthreads();
    // constant bias channel: h[*][100] = 1.0 in both buffers
    if (tid < 32) hlds[tid >> 4][(tid & 15) * KS + 100] = (_Float16)1.0f;

    // ---- chunked W staging (one gate per chunk) + frag extraction ----
    // Wstg[u][k] = Whh[s*100+u][k]*sc ; k=100 holds (bih+bhh)*sc ; rest 0.
    f16x8 wfrag[4][4];
    for (int s = 0; s < 4; ++s) {
        const float sc = (s == 2) ? (-2.0f * LOG2E) : (-LOG2E);
        for (int idx = tid; idx < 10100; idx += 512) {
            if (idx < 10000) {
                int uu = idx / 100, k = idx - uu * 100;
                Wstg[uu * KS + k] = (_Float16)(Whh[(s * 100 + uu) * 100 + k] * sc);
            } else {
                int uu = idx - 10000;
                Wstg[uu * KS + 100] =
                    (_Float16)((bih[s * 100 + uu] + bhh[s * 100 + uu]) * sc);
            }
        }
        __syncthreads();
        #pragma unroll
        for (int ks = 0; ks < 4; ++ks)
            wfrag[s][ks] = *(const f16x8*)&Wstg[u * KS + ks * 32 + g * 8];
        __syncthreads();
    }

    // ---- xq: x-part of gate pre-acts (bias lives in channel 100 now),
    //      pre-scaled, packed to f16x2 (8 regs) ----
    unsigned xqp[4][2];
    float creg[4] = {0.f, 0.f, 0.f, 0.f};
    float wd = 0.0f;
    {
        float xq[4][4];
        #pragma unroll
        for (int s = 0; s < 4; ++s)
            #pragma unroll
            for (int r = 0; r < 4; ++r) xq[s][r] = 0.0f;
        if (u < 100) {
            wd = Wd[u];
            for (int k = 0; k < 30; ++k) {
                float xv[4];
                #pragma unroll
                for (int r = 0; r < 4; ++r) xv[r] = x[(b0 + 4 * g + r) * 30 + k];
                #pragma unroll
                for (int s = 0; s < 4; ++s) {
                    float wv = Wih[(s * 100 + u) * 30 + k];
                    #pragma unroll
                    for (int r = 0; r < 4; ++r) xq[s][r] += xv[r] * wv;
                }
            }
            #pragma unroll
            for (int s = 0; s < 4; ++s) {
                float sc = (s == 2) ? (-2.0f * LOG2E) : (-LOG2E);
                #pragma unroll
                for (int r = 0; r < 4; ++r) xq[s][r] *= sc;
            }
        }
        #pragma unroll
        for (int s = 0; s < 4; ++s) {
            xqp[s][0] = pk_f16(xq[s][0], xq[s][1]);
            xqp[s][1] = pk_f16(xq[s][2], xq[s][3]);
        }
    }
    const float bdv = bd[0];
    __syncthreads();   // ch-100 init + staging fully visible

    const int afb = c * KS + g * 8;          // A-frag base (+ks*32)
    const int hwb = (4 * g) * KS + u;        // h-write base (+r*KS)

    // ---- recurrence: one barrier per step, no VMEM in loop ----
    for (int t = 0; t < 100; ++t) {
        const _Float16* hr = hlds[t & 1];
        _Float16*       hw = hlds[(t & 1) ^ 1];

        f16x8 af[4];
        #pragma unroll
        for (int ks = 0; ks < 4; ++ks)
            af[ks] = *(const f16x8*)&hr[afb + ks * 32];

        // drain step t-1 -> outb (2 lanes per wave; LDS only)
        if (t > 0 && l < 2) {
            const float* ps = &part[(t - 1) & 1][2 * w + l][0];
            f32x4 v0 = *(const f32x4*)ps;
            f32x4 v1 = *(const f32x4*)(ps + 4);
            outb[(2 * w + l) * 100 + (t - 1)] =
                v0[0] + v0[1] + v0[2] + v0[3] + v1[0] + v1[1] + v1[2] + v1[3] + bdv;
        }

        // 16 MFMAs: acc[s] = xq[s] + h @ W_s
        f32x4 acc[4];
        #pragma unroll
        for (int s = 0; s < 4; ++s) {
            f16x2v p0 = __builtin_bit_cast(f16x2v, xqp[s][0]);
            f16x2v p1 = __builtin_bit_cast(f16x2v, xqp[s][1]);
            f32x4 a = {(float)p0[0], (float)p0[1], (float)p1[0], (float)p1[1]};
            #pragma unroll
            for (int ks = 0; ks < 4; ++ks)
                a = __builtin_amdgcn_mfma_f32_16x16x32_f16(
                        af[ks], wfrag[s][ks], a, 0, 0, 0);
            acc[s] = a;
        }

        // activations (pre-acts pre-scaled by -log2e / -2log2e)
        float po[4];
        #pragma unroll
        for (int r = 0; r < 4; ++r) {
            float ig = rcp_(exp2_(acc[0][r]) + 1.0f);
            float fg = rcp_(exp2_(acc[1][r]) + 1.0f);
            float gg = fmaf(2.0f, rcp_(exp2_(acc[2][r]) + 1.0f), -1.0f);
            float og = rcp_(exp2_(acc[3][r]) + 1.0f);
            float cg = fmaf(fg, creg[r], ig * gg);
            creg[r] = cg;
            float th = fmaf(2.0f, rcp_(exp2_(cg * (-2.0f * LOG2E)) + 1.0f), -1.0f);
            float hv = og * th;
            po[r] = hv * wd;
            if (u < 100) hw[hwb + r * KS] = (_Float16)hv;   // keep ch>=100 intact
        }

        // reduce po over the 16 c-lanes (DPP row_ror butterfly)
        #pragma unroll
        for (int r = 0; r < 4; ++r) {
            po[r] = dpp_add<0x128>(po[r]);
            po[r] = dpp_add<0x124>(po[r]);
            po[r] = dpp_add<0x122>(po[r]);
            po[r] = dpp_add<0x121>(po[r]);
        }
        if (c == 0) {
            #pragma unroll
            for (int r = 0; r < 4; ++r)
                part[t & 1][4 * g + r][w] = po[r];
        }
        __syncthreads();   // h(t) + part(t) visible (lgkm only)
    }

    // final drain t=99 (buffer 1), then coalesced global write
    if (l < 2) {
        const float* ps = &part[1][2 * w + l][0];
        f32x4 v0 = *(const f32x4*)ps;
        f32x4 v1 = *(const f32x4*)(ps + 4);
        outb[(2 * w + l) * 100 + 99] =
            v0[0] + v0[1] + v0[2] + v0[3] + v1[0] + v1[1] + v1[2] + v1[3] + bdv;
    }
    __syncthreads();
    for (int i = tid; i < 1600; i += 512)
        out[b0 * 100 + i] = outb[i];
}

extern "C" void kernel_launch(void* const* d_in, const int* in_sizes, int n_in,
                              void* d_out, int out_size, void* d_ws, size_t ws_size,
                              hipStream_t stream) {
    (void)in_sizes; (void)n_in; (void)out_size; (void)d_ws; (void)ws_size;
    const float* x   = (const float*)d_in[0];
    const float* Wih = (const float*)d_in[1];
    const float* Whh = (const float*)d_in[2];
    const float* bih = (const float*)d_in[3];
    const float* bhh = (const float*)d_in[4];
    const float* Wd  = (const float*)d_in[5];
    const float* bd  = (const float*)d_in[6];
    lstm_kernel<<<dim3(512), dim3(512), 0, stream>>>(
        x, Wih, Whh, bih, bhh, Wd, bd, (float*)d_out);
}

// Round 8
// 179.050 us; speedup vs baseline: 1.1622x; 1.1622x over previous
//
#include <hip/hip_runtime.h>

// RecurrentDecoder: B=8192, T=100, I=30, H=100.
// Fused transpose-free LSTM, fp16 MFMA (16x16x32), per-gate column blocks.
// 512 blocks x 256 threads (4 waves): B-tile=16, 32 units/wave (8 cells/lane),
// 2 independent blocks/CU -> decorrelated barriers fill VALU idle.
// W frags (AGPR) + xq + c-state register-resident; merged-rcp activations
// (8 trans/cell); no VMEM in step loop; t-loop unrolled x2.

#define LOG2E 1.44269504088896340736f

typedef _Float16 f16x8 __attribute__((ext_vector_type(8)));
typedef float    f32x4 __attribute__((ext_vector_type(4)));

__device__ __forceinline__ float rcp_(float x) { return __builtin_amdgcn_rcpf(x); }
__device__ __forceinline__ float exp2_(float x) { return __builtin_amdgcn_exp2f(x); }

__device__ __forceinline__ unsigned pk_f16(float a, float b) {
    return __builtin_bit_cast(unsigned, __builtin_amdgcn_cvt_pkrtz(a, b));
}

template<int CTRL>
__device__ __forceinline__ float dpp_add(float x) {
    float t = __int_as_float(__builtin_amdgcn_update_dpp(
        0, __float_as_int(x), CTRL, 0xF, 0xF, true));
    return x + t;
}

#define KS 136   // f16 k-stride (272 B, 16B-aligned)

__global__ __launch_bounds__(256, 2) void lstm_kernel(
    const float* __restrict__ x, const float* __restrict__ Wih,
    const float* __restrict__ Whh, const float* __restrict__ bih,
    const float* __restrict__ bhh, const float* __restrict__ Wd,
    const float* __restrict__ bd, float* __restrict__ out)
{
    __shared__ __align__(16) _Float16 Wstg[128 * KS];     // 34816 B (gate chunk)
    __shared__ __align__(16) _Float16 hlds[2][16 * KS];   //  8704 B (dbuf)
    __shared__ __align__(16) float part[2][16][4];        //   512 B
    __shared__ float outb[16 * 100];                      //  6400 B
    // total ~59 KB -> 2 blocks/CU

    const int tid = threadIdx.x;
    const int w   = tid >> 6;      // wave 0..3 -> units w*32..w*32+31
    const int l   = tid & 63;
    const int g   = l >> 4;        // 0..3 -> rows 4g..4g+3
    const int c   = l & 15;
    const int b0  = blockIdx.x * 16;

    // ---- zero LDS (covers all padding; h(-1)=0) ----
    for (int i = tid; i < 128 * KS / 2; i += 256) ((unsigned*)Wstg)[i] = 0u;
    for (int i = tid; i < 2 * 16 * KS / 2; i += 256) ((unsigned*)&hlds[0][0])[i] = 0u;
    __syncthreads();

    // ---- chunked W staging (one gate per chunk), pre-scaled; interleaved
    //      unit->col permutation: col = 32*(u>>5) + 16*(u&1) + ((u&31)>>1)
    //      so lane (w,c) of tile nt holds unit u = w*32 + 2c + nt. ----
    f16x8 wfrag[2][4][4];
    for (int s = 0; s < 4; ++s) {
        const float sc = (s == 2) ? (-2.0f * LOG2E) : (-LOG2E);
        for (int idx = tid; idx < 10000; idx += 256) {
            int uu = idx / 100, k = idx - uu * 100;
            int col = 32 * (uu >> 5) + 16 * (uu & 1) + ((uu & 31) >> 1);
            Wstg[col * KS + k] = (_Float16)(Whh[(s * 100 + uu) * 100 + k] * sc);
        }
        __syncthreads();
        #pragma unroll
        for (int nt = 0; nt < 2; ++nt)
            #pragma unroll
            for (int ks = 0; ks < 4; ++ks)
                wfrag[nt][s][ks] = *(const f16x8*)
                    &Wstg[(w * 32 + nt * 16 + c) * KS + ks * 32 + g * 8];
        __syncthreads();
    }

    // ---- xq: pre-scaled gate pre-acts from x (+bias), C-frag coords ----
    const int row0 = b0 + 4 * g;
    f32x4 xq[2][4];
    float creg[2][4];
    float wd[2];
    #pragma unroll
    for (int nt = 0; nt < 2; ++nt) {
        int u = w * 32 + 2 * c + nt;
        wd[nt] = (u < 100) ? Wd[u] : 0.0f;
        #pragma unroll
        for (int s = 0; s < 4; ++s) xq[nt][s] = (f32x4){0.f, 0.f, 0.f, 0.f};
        #pragma unroll
        for (int r = 0; r < 4; ++r) creg[nt][r] = 0.0f;
    }
    for (int k = 0; k < 30; ++k) {
        float xv[4];
        #pragma unroll
        for (int r = 0; r < 4; ++r) xv[r] = x[(row0 + r) * 30 + k];
        #pragma unroll
        for (int nt = 0; nt < 2; ++nt) {
            int u = w * 32 + 2 * c + nt;
            if (u < 100) {
                #pragma unroll
                for (int s = 0; s < 4; ++s) {
                    float wv = Wih[(s * 100 + u) * 30 + k];
                    #pragma unroll
                    for (int r = 0; r < 4; ++r) xq[nt][s][r] += xv[r] * wv;
                }
            }
        }
    }
    #pragma unroll
    for (int nt = 0; nt < 2; ++nt) {
        int u = w * 32 + 2 * c + nt;
        if (u < 100) {
            #pragma unroll
            for (int s = 0; s < 4; ++s) {
                float sc = (s == 2) ? (-2.0f * LOG2E) : (-LOG2E);
                float b  = bih[s * 100 + u] + bhh[s * 100 + u];
                #pragma unroll
                for (int r = 0; r < 4; ++r)
                    xq[nt][s][r] = (xq[nt][s][r] + b) * sc;
            }
        }
    }
    const float bdv = bd[0];
    __syncthreads();

    const int afb = c * KS + g * 8;                 // A-frag base (+ks*32)
    const int hwc = w * 32 + 2 * c;                 // packed h channel pair

    // one LSTM step; P = buffer parity (compile-time 0/1), tcur = step index
#define STEP(P, TCUR)                                                          \
    {                                                                          \
        const _Float16* hr = &hlds[(P)][0];                                    \
        _Float16*       hw = &hlds[(P) ^ 1][0];                                \
        f16x8 af[4];                                                           \
        _Pragma("unroll")                                                      \
        for (int ks = 0; ks < 4; ++ks)                                         \
            af[ks] = *(const f16x8*)&hr[afb + ks * 32];                        \
        if ((TCUR) > 0 && l < 4) {                                             \
            f32x4 v = *(const f32x4*)&part[(P) ^ 1][4 * w + l][0];             \
            outb[(4 * w + l) * 100 + (TCUR) - 1] =                             \
                v[0] + v[1] + v[2] + v[3] + bdv;                               \
        }                                                                      \
        f32x4 acc[2][4];                                                       \
        _Pragma("unroll")                                                      \
        for (int nt = 0; nt < 2; ++nt)                                         \
            _Pragma("unroll")                                                  \
            for (int s = 0; s < 4; ++s) {                                      \
                f32x4 a = xq[nt][s];                                           \
                _Pragma("unroll")                                              \
                for (int ks = 0; ks < 4; ++ks)                                 \
                    a = __builtin_amdgcn_mfma_f32_16x16x32_f16(                \
                            af[ks], wfrag[nt][s][ks], a, 0, 0, 0);             \
                acc[nt][s] = a;                                                \
            }                                                                  \
        float po[4];                                                           \
        _Pragma("unroll")                                                      \
        for (int r = 0; r < 4; ++r) {                                          \
            float hv[2];                                                       \
            _Pragma("unroll")                                                  \
            for (int nt = 0; nt < 2; ++nt) {                                   \
                float A  = exp2_(acc[nt][0][r]);                               \
                float F  = exp2_(acc[nt][1][r]);                               \
                float G  = exp2_(acc[nt][2][r]);                               \
                float O  = exp2_(acc[nt][3][r]);                               \
                float fg = rcp_(1.0f + F);                                     \
                float igg = (1.0f - G) * rcp_((1.0f + A) * (1.0f + G));        \
                float cg = fmaf(fg, creg[nt][r], igg);                         \
                creg[nt][r] = cg;                                              \
                float C2 = exp2_(cg * (-2.0f * LOG2E));                        \
                hv[nt] = (1.0f - C2) * rcp_((1.0f + O) * (1.0f + C2));         \
            }                                                                  \
            po[r] = fmaf(hv[0], wd[0], hv[1] * wd[1]);                         \
            *(unsigned*)&hw[(4 * g + r) * KS + hwc] = pk_f16(hv[0], hv[1]);    \
        }                                                                      \
        _Pragma("unroll")                                                      \
        for (int r = 0; r < 4; ++r) {                                          \
            po[r] = dpp_add<0x128>(po[r]);                                     \
            po[r] = dpp_add<0x124>(po[r]);                                     \
            po[r] = dpp_add<0x122>(po[r]);                                     \
            po[r] = dpp_add<0x121>(po[r]);                                     \
        }                                                                      \
        if (c == 0) {                                                          \
            _Pragma("unroll")                                                  \
            for (int r = 0; r < 4; ++r)                                        \
                part[(P)][4 * g + r][w] = po[r];                               \
        }                                                                      \
        __syncthreads();                                                       \
    }

    for (int t2 = 0; t2 < 50; ++t2) {
        STEP(0, 2 * t2);
        STEP(1, 2 * t2 + 1);
    }
#undef STEP

    // final drain t=99 (wrote part[1]), then coalesced global write
    if (l < 4) {
        f32x4 v = *(const f32x4*)&part[1][4 * w + l][0];
        outb[(4 * w + l) * 100 + 99] = v[0] + v[1] + v[2] + v[3] + bdv;
    }
    __syncthreads();
    for (int i = tid; i < 1600; i += 256)
        out[b0 * 100 + i] = outb[i];
}

extern "C" void kernel_launch(void* const* d_in, const int* in_sizes, int n_in,
                              void* d_out, int out_size, void* d_ws, size_t ws_size,
                              hipStream_t stream) {
    (void)in_sizes; (void)n_in; (void)out_size; (void)d_ws; (void)ws_size;
    const float* x   = (const float*)d_in[0];
    const float* Wih = (const float*)d_in[1];
    const float* Whh = (const float*)d_in[2];
    const float* bih = (const float*)d_in[3];
    const float* bhh = (const float*)d_in[4];
    const float* Wd  = (const float*)d_in[5];
    const float* bd  = (const float*)d_in[6];
    lstm_kernel<<<dim3(512), dim3(256), 0, stream>>>(
        x, Wih, Whh, bih, bhh, Wd, bd, (float*)d_out);
}

// Round 9
// 172.758 us; speedup vs baseline: 1.2045x; 1.0364x over previous
//
#include <hip/hip_runtime.h>

// RecurrentDecoder: B=8192, T=100, I=30, H=100.
// Fused transpose-free LSTM, fp16 MFMA (16x16x32), per-gate column blocks.
// 512 blocks x 256 threads (4 waves): B-tile=16, 32 units/wave (8 cells/lane).
// R9: ks-outer MFMA interleave (8-way ILP, no latency chains); po computed by
// the MFMA itself via W_d in dead column 98 (no DPP/part/drain); merged-rcp
// LSTM cell (7 trans/cell). One barrier per step; no VMEM in loop.

#define LOG2E 1.44269504088896340736f

typedef _Float16 f16x8 __attribute__((ext_vector_type(8)));
typedef float    f32x4 __attribute__((ext_vector_type(4)));

__device__ __forceinline__ float rcp_(float x) { return __builtin_amdgcn_rcpf(x); }
__device__ __forceinline__ float exp2_(float x) { return __builtin_amdgcn_exp2f(x); }

__device__ __forceinline__ unsigned pk_f16(float a, float b) {
    return __builtin_bit_cast(unsigned, __builtin_amdgcn_cvt_pkrtz(a, b));
}

#define KS 136   // f16 k-stride (272 B, 16B-aligned)

__global__ __launch_bounds__(256, 2) void lstm_kernel(
    const float* __restrict__ x, const float* __restrict__ Wih,
    const float* __restrict__ Whh, const float* __restrict__ bih,
    const float* __restrict__ bhh, const float* __restrict__ Wd,
    const float* __restrict__ bd, float* __restrict__ out)
{
    __shared__ __align__(16) _Float16 Wstg[128 * KS];     // 34816 B (gate chunk)
    __shared__ __align__(16) _Float16 hlds[2][16 * KS];   //  8704 B (dbuf)
    __shared__ float outb[16 * 100];                      //  6400 B
    // total ~58.6 KB -> 2 blocks/CU

    const int tid = threadIdx.x;
    const int w   = tid >> 6;      // wave 0..3 -> unit-cols w*32..w*32+31
    const int l   = tid & 63;
    const int g   = l >> 4;        // 0..3 -> rows 4g..4g+3
    const int c   = l & 15;
    const int b0  = blockIdx.x * 16;
    const bool wpo = (w == 3) && (c == 2);   // owner of the po column (col 98)

    // ---- zero LDS (covers all padding; h(-1)=0) ----
    for (int i = tid; i < 128 * KS / 2; i += 256) ((unsigned*)Wstg)[i] = 0u;
    for (int i = tid; i < 2 * 16 * KS / 2; i += 256) ((unsigned*)&hlds[0][0])[i] = 0u;
    __syncthreads();

    // ---- chunked W staging (one gate per chunk), pre-scaled; interleaved
    //      unit->col permutation: col = 32*(u>>5) + 16*(u&1) + ((u&31)>>1)
    //      (lane (w,c) of tile nt holds unit u = w*32 + 2c + nt).
    //      Dead col 98 (=permuted u=100) holds W_d UNSCALED -> MFMA computes po. ----
    f16x8 wfrag[2][4][4];
    for (int s = 0; s < 4; ++s) {
        const float sc = (s == 2) ? (-2.0f * LOG2E) : (-LOG2E);
        for (int idx = tid; idx < 10000; idx += 256) {
            int uu = idx / 100, k = idx - uu * 100;
            int col = 32 * (uu >> 5) + 16 * (uu & 1) + ((uu & 31) >> 1);
            Wstg[col * KS + k] = (_Float16)(Whh[(s * 100 + uu) * 100 + k] * sc);
        }
        if (s == 0)
            for (int k = tid; k < 100; k += 256)
                Wstg[98 * KS + k] = (_Float16)Wd[k];
        __syncthreads();
        #pragma unroll
        for (int nt = 0; nt < 2; ++nt)
            #pragma unroll
            for (int ks = 0; ks < 4; ++ks)
                wfrag[nt][s][ks] = *(const f16x8*)
                    &Wstg[(w * 32 + nt * 16 + c) * KS + ks * 32 + g * 8];
        __syncthreads();
    }

    // ---- xq: pre-scaled gate pre-acts from x (+bias), C-frag coords ----
    const int row0 = b0 + 4 * g;
    f32x4 xq[2][4];
    float creg[2][4];
    #pragma unroll
    for (int nt = 0; nt < 2; ++nt) {
        #pragma unroll
        for (int s = 0; s < 4; ++s) xq[nt][s] = (f32x4){0.f, 0.f, 0.f, 0.f};
        #pragma unroll
        for (int r = 0; r < 4; ++r) creg[nt][r] = 0.0f;
    }
    for (int k = 0; k < 30; ++k) {
        float xv[4];
        #pragma unroll
        for (int r = 0; r < 4; ++r) xv[r] = x[(row0 + r) * 30 + k];
        #pragma unroll
        for (int nt = 0; nt < 2; ++nt) {
            int u = w * 32 + 2 * c + nt;
            if (u < 100) {
                #pragma unroll
                for (int s = 0; s < 4; ++s) {
                    float wv = Wih[(s * 100 + u) * 30 + k];
                    #pragma unroll
                    for (int r = 0; r < 4; ++r) xq[nt][s][r] += xv[r] * wv;
                }
            }
        }
    }
    #pragma unroll
    for (int nt = 0; nt < 2; ++nt) {
        int u = w * 32 + 2 * c + nt;
        if (u < 100) {
            #pragma unroll
            for (int s = 0; s < 4; ++s) {
                float sc = (s == 2) ? (-2.0f * LOG2E) : (-LOG2E);
                float b  = bih[s * 100 + u] + bhh[s * 100 + u];
                #pragma unroll
                for (int r = 0; r < 4; ++r)
                    xq[nt][s][r] = (xq[nt][s][r] + b) * sc;
            }
        }
    }
    const float bdv = bd[0];
    __syncthreads();

    const int afb = c * KS + g * 8;                 // A-frag base (+ks*32)
    const int hwc = w * 32 + 2 * c;                 // packed h channel pair

    // one LSTM step; P = buffer parity (compile-time), TCUR = step index
#define STEP(P, TCUR)                                                          \
    {                                                                          \
        const _Float16* hr = &hlds[(P)][0];                                    \
        _Float16*       hw = &hlds[(P) ^ 1][0];                                \
        f16x8 af[4];                                                           \
        _Pragma("unroll")                                                      \
        for (int ks = 0; ks < 4; ++ks)                                         \
            af[ks] = *(const f16x8*)&hr[afb + ks * 32];                        \
        /* MFMA: ks-outer, 8 independent accs between dependent pairs */       \
        f32x4 acc[2][4];                                                       \
        _Pragma("unroll")                                                      \
        for (int nt = 0; nt < 2; ++nt)                                         \
            _Pragma("unroll")                                                  \
            for (int s = 0; s < 4; ++s)                                        \
                acc[nt][s] = __builtin_amdgcn_mfma_f32_16x16x32_f16(           \
                        af[0], wfrag[nt][s][0], xq[nt][s], 0, 0, 0);           \
        _Pragma("unroll")                                                      \
        for (int ks = 1; ks < 4; ++ks)                                         \
            _Pragma("unroll")                                                  \
            for (int nt = 0; nt < 2; ++nt)                                     \
                _Pragma("unroll")                                              \
                for (int s = 0; s < 4; ++s)                                    \
                    acc[nt][s] = __builtin_amdgcn_mfma_f32_16x16x32_f16(       \
                            af[ks], wfrag[nt][s][ks], acc[nt][s], 0, 0, 0);    \
        /* po(t-1) = h(t-1)@W_d landed in acc[0][0] of the col-98 lane */      \
        if ((TCUR) > 0 && wpo) {                                               \
            _Pragma("unroll")                                                  \
            for (int r = 0; r < 4; ++r)                                        \
                outb[(4 * g + r) * 100 + (TCUR) - 1] = acc[0][0][r] + bdv;     \
        }                                                                      \
        /* activations: merged-rcp cell (5 exp2 + 2 rcp per cell) */           \
        _Pragma("unroll")                                                      \
        for (int r = 0; r < 4; ++r) {                                          \
            float hv[2];                                                       \
            _Pragma("unroll")                                                  \
            for (int nt = 0; nt < 2; ++nt) {                                   \
                float A  = exp2_(acc[nt][0][r]);                               \
                float F  = exp2_(acc[nt][1][r]);                               \
                float G  = exp2_(acc[nt][2][r]);                               \
                float O  = exp2_(acc[nt][3][r]);                               \
                float a1 = 1.0f + A, f1 = 1.0f + F;                            \
                float g1 = 1.0f + G, gm = 1.0f - G;                            \
                float ag  = a1 * g1;                                           \
                float num = fmaf(creg[nt][r], ag, gm * f1);                    \
                float cg  = num * rcp_(ag * f1);                               \
                creg[nt][r] = cg;                                              \
                float C2 = exp2_(cg * (-2.0f * LOG2E));                        \
                hv[nt] = (1.0f - C2) * rcp_((1.0f + O) * (1.0f + C2));         \
            }                                                                  \
            *(unsigned*)&hw[(4 * g + r) * KS + hwc] = pk_f16(hv[0], hv[1]);    \
        }                                                                      \
        __syncthreads();                                                       \
    }

    for (int t2 = 0; t2 < 50; ++t2) {
        STEP(0, 2 * t2);
        STEP(1, 2 * t2 + 1);
    }
#undef STEP

    // epilogue: po(99) via one more MFMA pass on final h (in hlds[0])
    {
        f16x8 af[4];
        #pragma unroll
        for (int ks = 0; ks < 4; ++ks)
            af[ks] = *(const f16x8*)&hlds[0][afb + ks * 32];
        f32x4 a = {0.f, 0.f, 0.f, 0.f};
        #pragma unroll
        for (int ks = 0; ks < 4; ++ks)
            a = __builtin_amdgcn_mfma_f32_16x16x32_f16(
                    af[ks], wfrag[0][0][ks], a, 0, 0, 0);
        if (wpo) {
            #pragma unroll
            for (int r = 0; r < 4; ++r)
                outb[(4 * g + r) * 100 + 99] = a[r] + bdv;
        }
    }
    __syncthreads();
    for (int i = tid; i < 1600; i += 256)
        out[b0 * 100 + i] = outb[i];
}

extern "C" void kernel_launch(void* const* d_in, const int* in_sizes, int n_in,
                              void* d_out, int out_size, void* d_ws, size_t ws_size,
                              hipStream_t stream) {
    (void)in_sizes; (void)n_in; (void)out_size; (void)d_ws; (void)ws_size;
    const float* x   = (const float*)d_in[0];
    const float* Wih = (const float*)d_in[1];
    const float* Whh = (const float*)d_in[2];
    const float* bih = (const float*)d_in[3];
    const float* bhh = (const float*)d_in[4];
    const float* Wd  = (const float*)d_in[5];
    const float* bd  = (const float*)d_in[6];
    lstm_kernel<<<dim3(512), dim3(256), 0, stream>>>(
        x, Wih, Whh, bih, bhh, Wd, bd, (float*)d_out);
}